// Round 1
// baseline (874.600 us; speedup 1.0000x reference)
//
#include <hip/hip_runtime.h>
#include <cmath>

#define N_TOT 30000
#define N0_   18000
#define R_    5
#define E_    600000
#define RN    (R_ * N_TOT)
#define NC_   (N_TOT * 8)        // logits elements
#define NX_   (N_TOT * 128)      // x elements

// ---------------------------------------------------------------------------
// init: u = 1/R, act[0] = 1
// ---------------------------------------------------------------------------
__global__ void init_kernel(float* ug, int* act) {
    if (threadIdx.x < 5) ug[threadIdx.x] = 0.2f;
    if (threadIdx.x == 0) act[0] = 1;
}

// ---------------------------------------------------------------------------
// Fused MLP: h = feat@W + b ; t1 = h@Wm1+bm1 ; LN+ReLU ; t2 = z@Wm2+bm2 ;
// per-row standardize (ddof=1) with nan_to_num -> xout
// One 128-thread block per node row.
// ---------------------------------------------------------------------------
__global__ __launch_bounds__(128) void mlp_kernel(
    const float* __restrict__ feat0, const float* __restrict__ feat1,
    const float* __restrict__ W0, const float* __restrict__ b0,
    const float* __restrict__ W1, const float* __restrict__ b1,
    const float* __restrict__ Wm1, const float* __restrict__ bm1,
    const float* __restrict__ Wm2, const float* __restrict__ bm2,
    float* __restrict__ xout)
{
    const int row = blockIdx.x;
    const int j = threadIdx.x;
    const int lane = j & 63, w = j >> 6;
    __shared__ float sf[256];
    __shared__ float sv[128];
    __shared__ float sr[2];

    const float* feat; const float* W; int K; float bias;
    if (row < N0_) { feat = feat0 + (size_t)row * 256; W = W0; K = 256; bias = b0[j]; }
    else           { feat = feat1 + (size_t)(row - N0_) * 128; W = W1; K = 128; bias = b1[j]; }
    for (int k = j; k < K; k += 128) sf[k] = feat[k];
    __syncthreads();

    float acc = bias;
    {
        const float4* sf4 = (const float4*)sf;
        for (int k4 = 0; k4 < (K >> 2); ++k4) {
            float4 h4 = sf4[k4];
            int kb = k4 * 4;
            acc = fmaf(h4.x, W[(kb + 0) * 128 + j], acc);
            acc = fmaf(h4.y, W[(kb + 1) * 128 + j], acc);
            acc = fmaf(h4.z, W[(kb + 2) * 128 + j], acc);
            acc = fmaf(h4.w, W[(kb + 3) * 128 + j], acc);
        }
    }
    sv[j] = acc;
    __syncthreads();

    float t1 = bm1[j];
    {
        const float4* sv4 = (const float4*)sv;
        for (int k4 = 0; k4 < 32; ++k4) {
            float4 h4 = sv4[k4];
            int kb = k4 * 4;
            t1 = fmaf(h4.x, Wm1[(kb + 0) * 128 + j], t1);
            t1 = fmaf(h4.y, Wm1[(kb + 1) * 128 + j], t1);
            t1 = fmaf(h4.z, Wm1[(kb + 2) * 128 + j], t1);
            t1 = fmaf(h4.w, Wm1[(kb + 3) * 128 + j], t1);
        }
    }
    // layernorm (biased var) + relu
    float s = t1;
    for (int o = 32; o > 0; o >>= 1) s += __shfl_down(s, o, 64);
    if (lane == 0) sr[w] = s;
    __syncthreads();
    float m = (sr[0] + sr[1]) * (1.0f / 128.0f);
    float d = t1 - m;
    float s2 = d * d;
    for (int o = 32; o > 0; o >>= 1) s2 += __shfl_down(s2, o, 64);
    __syncthreads();
    if (lane == 0) sr[w] = s2;
    __syncthreads();
    float var = (sr[0] + sr[1]) * (1.0f / 128.0f);
    float z = fmaxf(d / sqrtf(var + 1e-5f), 0.0f);
    __syncthreads();
    sv[j] = z;
    __syncthreads();

    float t2 = bm2[j];
    {
        const float4* sv4 = (const float4*)sv;
        for (int k4 = 0; k4 < 32; ++k4) {
            float4 h4 = sv4[k4];
            int kb = k4 * 4;
            t2 = fmaf(h4.x, Wm2[(kb + 0) * 128 + j], t2);
            t2 = fmaf(h4.y, Wm2[(kb + 1) * 128 + j], t2);
            t2 = fmaf(h4.z, Wm2[(kb + 2) * 128 + j], t2);
            t2 = fmaf(h4.w, Wm2[(kb + 3) * 128 + j], t2);
        }
    }
    // standardize, std with ddof=1, nan_to_num
    float su = t2;
    for (int o = 32; o > 0; o >>= 1) su += __shfl_down(su, o, 64);
    __syncthreads();
    if (lane == 0) sr[w] = su;
    __syncthreads();
    float mu = (sr[0] + sr[1]) * (1.0f / 128.0f);
    float dd = t2 - mu;
    float q = dd * dd;
    for (int o = 32; o > 0; o >>= 1) q += __shfl_down(q, o, 64);
    __syncthreads();
    if (lane == 0) sr[w] = q;
    __syncthreads();
    float ss = sr[0] + sr[1];
    float sd = sqrtf(ss * (1.0f / 127.0f));
    float r = dd / sd;
    if (!(fabsf(r) <= 3.402823466e38f)) {
        r = (r != r) ? 0.0f : ((r > 0.0f) ? 3.402823466e38f : -3.402823466e38f);
    }
    xout[(size_t)row * 128 + j] = r;
}

// ---------------------------------------------------------------------------
// degree histogram over key = rel*N + src
// ---------------------------------------------------------------------------
__global__ void deg_kernel(const int* __restrict__ src, const int* __restrict__ rel,
                           int* __restrict__ deg_i)
{
    int e = blockIdx.x * 256 + threadIdx.x;
    if (e >= E_) return;
    atomicAdd(&deg_i[rel[e] * N_TOT + src[e]], 1);
}

__global__ void dinv_kernel(const int* __restrict__ deg_i, float* __restrict__ dinv)
{
    int i = blockIdx.x * 256 + threadIdx.x;
    if (i >= RN) return;
    int dg = deg_i[i];
    dinv[i] = (dg > 0) ? 1.0f / sqrtf((float)dg) : 0.0f;
}

// ---------------------------------------------------------------------------
// single-block exclusive scan of deg_i (RN elems) -> rp[RN+1]
// ---------------------------------------------------------------------------
__global__ __launch_bounds__(1024) void scan_kernel(const int* __restrict__ cnt,
                                                    int* __restrict__ rp)
{
    __shared__ int wsum[16];
    __shared__ int s_carry;
    const int t = threadIdx.x, lane = t & 63, w = t >> 6;
    if (t == 0) s_carry = 0;
    __syncthreads();
    const int CH = 8192;
    for (int base = 0; base < RN; base += CH) {
        int v[8]; int s = 0;
        const int i0 = base + t * 8;
        #pragma unroll
        for (int i = 0; i < 8; ++i) { int ii = i0 + i; v[i] = (ii < RN) ? cnt[ii] : 0; s += v[i]; }
        int sc = s;
        #pragma unroll
        for (int o = 1; o < 64; o <<= 1) { int tmp = __shfl_up(sc, o, 64); if (lane >= o) sc += tmp; }
        if (lane == 63) wsum[w] = sc;
        __syncthreads();
        int woff = 0;
        for (int i = 0; i < w; ++i) woff += wsum[i];
        int run = s_carry + woff + (sc - s);
        #pragma unroll
        for (int i = 0; i < 8; ++i) { int ii = i0 + i; if (ii < RN) rp[ii] = run; run += v[i]; }
        int chunk_total = woff + sc;   // valid for t==1023
        __syncthreads();
        if (t == 1023) s_carry += chunk_total;
        __syncthreads();
    }
    if (threadIdx.x == 0) rp[RN] = s_carry;
}

// ---------------------------------------------------------------------------
// counting-sort scatter into CSR keyed by rel*N+src
// ---------------------------------------------------------------------------
__global__ void scatter_kernel(const int* __restrict__ src, const int* __restrict__ dst,
                               const int* __restrict__ rel, const int* __restrict__ rp,
                               int* __restrict__ fill, const int* __restrict__ deg_i,
                               const float* __restrict__ dinv,
                               int* __restrict__ csr_dst, float* __restrict__ csr_w,
                               float* __restrict__ csr_edinv)
{
    int e = blockIdx.x * 256 + threadIdx.x;
    if (e >= E_) return;
    int s = src[e], r = rel[e], d = dst[e];
    int key = r * N_TOT + s;
    int pos = rp[key] + atomicAdd(&fill[key], 1);
    csr_dst[pos] = d;
    csr_w[pos] = 1.0f / (float)deg_i[key];
    csr_edinv[pos] = dinv[key] * dinv[r * N_TOT + d];
}

// ---------------------------------------------------------------------------
// tv: per-wave node loop; per-lane partial accumulators for node/edge terms
// ---------------------------------------------------------------------------
__global__ __launch_bounds__(256) void tv_kernel(
    const float* __restrict__ x, const int* __restrict__ rp,
    const int* __restrict__ csr_dst, const float* __restrict__ csr_edinv,
    const int* __restrict__ act, int k, float* __restrict__ accbuf)
{
    if (act[k] == 0) return;
    const int lane = threadIdx.x & 63;
    const int wv = threadIdx.x >> 6;
    const int wid = blockIdx.x * 4 + wv;
    const int nw = gridDim.x * 4;
    float na[5] = {0, 0, 0, 0, 0};
    float ea[5] = {0, 0, 0, 0, 0};
    for (int n = wid; n < N_TOT; n += nw) {
        const float2 xs = ((const float2*)(x + (size_t)n * 128))[lane];
        const float p = fmaf(xs.x, xs.x, xs.y * xs.y);
        #pragma unroll
        for (int r = 0; r < 5; ++r) {
            const int e0 = rp[r * N_TOT + n];
            const int e1 = rp[r * N_TOT + n + 1];
            if (e1 > e0) na[r] += p;
            float acc = 0.0f;
            for (int e = e0; e < e1; ++e) {
                const int dn = csr_dst[e];
                const float2 xd = ((const float2*)(x + (size_t)dn * 128))[lane];
                const float pe = fmaf(xs.x, xd.x, xs.y * xd.y);
                acc = fmaf(csr_edinv[e], pe, acc);
            }
            ea[r] += acc;
        }
    }
    __shared__ float sacc[4][10];
    #pragma unroll
    for (int r = 0; r < 5; ++r) {
        float a = na[r], b = ea[r];
        for (int o = 32; o > 0; o >>= 1) {
            a += __shfl_down(a, o, 64);
            b += __shfl_down(b, o, 64);
        }
        if (lane == 0) { sacc[wv][r] = a; sacc[wv][5 + r] = b; }
    }
    __syncthreads();
    if (threadIdx.x < 10) {
        float t = sacc[0][threadIdx.x] + sacc[1][threadIdx.x] +
                  sacc[2][threadIdx.x] + sacc[3][threadIdx.x];
        atomicAdd(&accbuf[threadIdx.x], t);
    }
}

// ---------------------------------------------------------------------------
// scalar: w from accumulators, mirror descent on u, still flag
// ---------------------------------------------------------------------------
__global__ void scalar_kernel(const float* __restrict__ accbuf, float* __restrict__ u,
                              float* __restrict__ c_l1, int* __restrict__ act, int k)
{
    if (threadIdx.x != 0 || blockIdx.x != 0) return;
    int a = act[k];
    double w[5]; double l1 = 0.0;
    for (int r = 0; r < 5; ++r) {
        w[r] = ((double)accbuf[r] - (double)accbuf[5 + r]) / 30000.0;
        l1 += fabs(w[r]);
    }
    if (k == 0) c_l1[0] = (float)l1;
    if (!a) { act[k + 1] = 0; return; }
    double fi = l1 + 3.0;                       // ratio = 2*L2/L1 = 3
    double uu[5];
    for (int r = 0; r < 5; ++r) uu[r] = (double)u[r];
    bool mact = true;
    const double twolog5 = 3.2188758248682006;  // 2*ln(5)
    for (int t = 1; t <= 20; ++t) {
        double T = sqrt(twolog5 / ((double)t * fi * fi));
        double ta[5], sum = 0.0;
        for (int r = 0; r < 5; ++r) { ta[r] = uu[r] * exp(-T * (3.0 * uu[r] + w[r])); sum += ta[r]; }
        double diff = 0.0;
        for (int r = 0; r < 5; ++r) { double un = ta[r] / sum; double d0 = uu[r] - un; diff += d0 * d0; ta[r] = un; }
        diff = sqrt(diff);
        if (mact) { for (int r = 0; r < 5; ++r) uu[r] = ta[r]; }
        mact = mact && (diff >= 1e-3);
    }
    for (int r = 0; r < 5; ++r) u[r] = (float)uu[r];
    int still = (l1 / (double)c_l1[0] >= 0.3) ? 1 : 0;
    act[k + 1] = still;
}

// ---------------------------------------------------------------------------
// msg: per-wave node loop, 5 static-rel CSR segments, writes msg buffer
// ---------------------------------------------------------------------------
__global__ __launch_bounds__(256) void msg_kernel(
    const float* __restrict__ x, const int* __restrict__ rp,
    const int* __restrict__ csr_dst, const float* __restrict__ csr_w,
    const float* __restrict__ ug, const int* __restrict__ act, int k,
    float* __restrict__ msg)
{
    if (act[k + 1] == 0) return;
    const int lane = threadIdx.x & 63;
    const int wid = blockIdx.x * 4 + (threadIdx.x >> 6);
    const int nw = gridDim.x * 4;
    const float u0 = ug[0], u1 = ug[1], u2 = ug[2], u3 = ug[3], u4 = ug[4];
    for (int n = wid; n < N_TOT; n += nw) {
        float ax = 0.0f, ay = 0.0f;
        #pragma unroll
        for (int r = 0; r < 5; ++r) {
            const float ur = (r == 0) ? u0 : (r == 1) ? u1 : (r == 2) ? u2 : (r == 3) ? u3 : u4;
            const int e0 = rp[r * N_TOT + n];
            const int e1 = rp[r * N_TOT + n + 1];
            for (int e = e0; e < e1; ++e) {
                const float wgt = ur * csr_w[e];
                const int dn = csr_dst[e];
                const float2 xd = ((const float2*)(x + (size_t)dn * 128))[lane];
                ax = fmaf(wgt, xd.x, ax);
                ay = fmaf(wgt, xd.y, ay);
            }
        }
        ((float2*)(msg + (size_t)n * 128))[lane] = make_float2(ax, ay);
    }
}

// ---------------------------------------------------------------------------
// x = x/(1+L1) + (L1/(1+L1))*msg   (only when still)
// ---------------------------------------------------------------------------
__global__ __launch_bounds__(256) void update_kernel(float* __restrict__ x,
                                                     const float* __restrict__ msg,
                                                     const int* __restrict__ act, int k)
{
    if (act[k + 1] == 0) return;
    int i = blockIdx.x * 256 + threadIdx.x;       // over NX_/4 float4s
    float4 xv = ((const float4*)x)[i];
    float4 mv = ((const float4*)msg)[i];
    const float cb = (float)(20.0 / 21.0);
    xv.x = xv.x / 21.0f + cb * mv.x;
    xv.y = xv.y / 21.0f + cb * mv.y;
    xv.z = xv.z / 21.0f + cb * mv.z;
    xv.w = xv.w / 21.0f + cb * mv.w;
    ((float4*)x)[i] = xv;
}

// ---------------------------------------------------------------------------
// epilogue: logits = x@Wout + bout ; write logits, x, u
// block = 256 threads = 2 nodes
// ---------------------------------------------------------------------------
__global__ __launch_bounds__(256) void final_kernel(const float* __restrict__ x,
                                                    const float* __restrict__ Wout,
                                                    const float* __restrict__ bout,
                                                    const float* __restrict__ ug,
                                                    float* __restrict__ out)
{
    const int nl = threadIdx.x >> 7;              // node-local 0/1
    const int n = blockIdx.x * 2 + nl;
    const int j = threadIdx.x & 127;
    const int lane = threadIdx.x & 63;
    const int wv = threadIdx.x >> 6;              // 0..3
    float xv = x[(size_t)n * 128 + j];
    out[(size_t)NC_ + (size_t)n * 128 + j] = xv;  // x output
    float p[8];
    #pragma unroll
    for (int c = 0; c < 8; ++c) p[c] = xv * Wout[j * 8 + c];
    #pragma unroll
    for (int c = 0; c < 8; ++c)
        for (int o = 32; o > 0; o >>= 1) p[c] += __shfl_down(p[c], o, 64);
    __shared__ float sp[4][8];
    if (lane == 0) {
        #pragma unroll
        for (int c = 0; c < 8; ++c) sp[wv][c] = p[c];
    }
    __syncthreads();
    if (j < 8) {
        int c = j;
        out[(size_t)n * 8 + c] = bout[c] + sp[2 * nl][c] + sp[2 * nl + 1][c];
    }
    if (blockIdx.x == 0 && threadIdx.x < 5)
        out[(size_t)NC_ + (size_t)NX_ + threadIdx.x] = ug[threadIdx.x];
}

// ---------------------------------------------------------------------------
extern "C" void kernel_launch(void* const* d_in, const int* in_sizes, int n_in,
                              void* d_out, int out_size, void* d_ws, size_t ws_size,
                              hipStream_t stream)
{
    const float* feat0 = (const float*)d_in[0];
    const float* feat1 = (const float*)d_in[1];
    const float* W0   = (const float*)d_in[2];
    const float* b0   = (const float*)d_in[3];
    const float* W1   = (const float*)d_in[4];
    const float* b1   = (const float*)d_in[5];
    const float* Wm1  = (const float*)d_in[6];
    const float* bm1  = (const float*)d_in[7];
    const float* Wm2  = (const float*)d_in[8];
    const float* bm2  = (const float*)d_in[9];
    const float* Wout = (const float*)d_in[10];
    const float* bout = (const float*)d_in[11];
    const int* src = (const int*)d_in[12];
    const int* dst = (const int*)d_in[13];
    const int* rel = (const int*)d_in[14];
    float* out = (float*)d_out;

    // workspace layout (~39 MiB total)
    char* p = (char*)d_ws;
    auto alloc = [&](size_t bytes) { char* q = p; p += (bytes + 255) & ~(size_t)255; return q; };
    float* xbuf      = (float*)alloc((size_t)NX_ * 4);
    float* msgbuf    = (float*)alloc((size_t)NX_ * 4);
    int*   deg_i     = (int*)  alloc((size_t)RN * 4);
    float* dinv      = (float*)alloc((size_t)RN * 4);
    int*   rp        = (int*)  alloc(((size_t)RN + 1) * 4);
    int*   fill      = (int*)  alloc((size_t)RN * 4);
    int*   csr_dst   = (int*)  alloc((size_t)E_ * 4);
    float* csr_w     = (float*)alloc((size_t)E_ * 4);
    float* csr_edinv = (float*)alloc((size_t)E_ * 4);
    float* accbuf    = (float*)alloc(64);
    float* ug        = (float*)alloc(64);
    float* c_l1      = (float*)alloc(64);
    int*   act       = (int*)  alloc(64);

    hipMemsetAsync(deg_i, 0, (size_t)RN * 4, stream);
    hipMemsetAsync(fill, 0, (size_t)RN * 4, stream);
    init_kernel<<<1, 64, 0, stream>>>(ug, act);

    mlp_kernel<<<N_TOT, 128, 0, stream>>>(feat0, feat1, W0, b0, W1, b1,
                                          Wm1, bm1, Wm2, bm2, xbuf);

    deg_kernel<<<(E_ + 255) / 256, 256, 0, stream>>>(src, rel, deg_i);
    dinv_kernel<<<(RN + 255) / 256, 256, 0, stream>>>(deg_i, dinv);
    scan_kernel<<<1, 1024, 0, stream>>>(deg_i, rp);
    scatter_kernel<<<(E_ + 255) / 256, 256, 0, stream>>>(src, dst, rel, rp, fill,
                                                         deg_i, dinv,
                                                         csr_dst, csr_w, csr_edinv);

    for (int k = 0; k < 8; ++k) {
        hipMemsetAsync(accbuf, 0, 64, stream);
        tv_kernel<<<2048, 256, 0, stream>>>(xbuf, rp, csr_dst, csr_edinv, act, k, accbuf);
        scalar_kernel<<<1, 64, 0, stream>>>(accbuf, ug, c_l1, act, k);
        msg_kernel<<<2048, 256, 0, stream>>>(xbuf, rp, csr_dst, csr_w, ug, act, k, msgbuf);
        update_kernel<<<NX_ / 4 / 256, 256, 0, stream>>>(xbuf, msgbuf, act, k);
    }

    final_kernel<<<N_TOT / 2, 256, 0, stream>>>(xbuf, Wout, bout, ug, out);
}

// Round 2
// 812.118 us; speedup vs baseline: 1.0769x; 1.0769x over previous
//
#include <hip/hip_runtime.h>
#include <cmath>

#define N_TOT 30000
#define N0_   18000
#define R_    5
#define E_    600000
#define RN    (R_ * N_TOT)
#define NC_   (N_TOT * 8)        // logits elements
#define NX_   (N_TOT * 128)      // x elements

// ---------------------------------------------------------------------------
// init: u = 1/R, act[0] = 1
// ---------------------------------------------------------------------------
__global__ void init_kernel(float* ug, int* act) {
    if (threadIdx.x < 5) ug[threadIdx.x] = 0.2f;
    if (threadIdx.x == 0) act[0] = 1;
}

// ---------------------------------------------------------------------------
// Fused MLP, 8 nodes per 128-thread block (weight reuse x8 -> L2 traffic /8).
// Layer1 activations via uniform scalar loads; layers 2-3 via LDS broadcast.
// ---------------------------------------------------------------------------
__global__ __launch_bounds__(128) void mlp_kernel(
    const float* __restrict__ feat0, const float* __restrict__ feat1,
    const float* __restrict__ W0, const float* __restrict__ b0,
    const float* __restrict__ W1, const float* __restrict__ b1,
    const float* __restrict__ Wm1, const float* __restrict__ bm1,
    const float* __restrict__ Wm2, const float* __restrict__ bm2,
    float* __restrict__ xout)
{
    const int j = threadIdx.x;
    const int lane = j & 63, wv_id = j >> 6;
    const int row0 = blockIdx.x * 8;

    __shared__ float sh[8][128];
    __shared__ float red[2][8];

    const bool is0 = (row0 < N0_);
    const float* __restrict__ fbase =
        is0 ? feat0 + (size_t)row0 * 256 : feat1 + (size_t)(row0 - N0_) * 128;
    const float* __restrict__ W = is0 ? W0 : W1;
    const int K = is0 ? 256 : 128;
    const float bias = is0 ? b0[j] : b1[j];

    // ---- layer 1: h = feat @ W + b ------------------------------------
    float acc[8];
    #pragma unroll
    for (int p = 0; p < 8; ++p) acc[p] = bias;

    for (int k = 0; k < K; k += 4) {
        float w0 = W[(k + 0) * 128 + j];
        float w1 = W[(k + 1) * 128 + j];
        float w2 = W[(k + 2) * 128 + j];
        float w3 = W[(k + 3) * 128 + j];
        #pragma unroll
        for (int p = 0; p < 8; ++p) {
            const float4 f4 = *(const float4*)(fbase + (size_t)p * K + k); // uniform -> s_load
            acc[p] = fmaf(f4.x, w0, acc[p]);
            acc[p] = fmaf(f4.y, w1, acc[p]);
            acc[p] = fmaf(f4.z, w2, acc[p]);
            acc[p] = fmaf(f4.w, w3, acc[p]);
        }
    }
    #pragma unroll
    for (int p = 0; p < 8; ++p) sh[p][j] = acc[p];
    __syncthreads();

    // ---- layer 2: t1 = h @ Wm1 + bm1 ----------------------------------
    float t1[8];
    #pragma unroll
    for (int p = 0; p < 8; ++p) t1[p] = bm1[j];
    for (int k = 0; k < 128; k += 4) {
        float w0 = Wm1[(k + 0) * 128 + j];
        float w1 = Wm1[(k + 1) * 128 + j];
        float w2 = Wm1[(k + 2) * 128 + j];
        float w3 = Wm1[(k + 3) * 128 + j];
        #pragma unroll
        for (int p = 0; p < 8; ++p) {
            const float4 f4 = *(const float4*)(&sh[p][k]);   // LDS broadcast
            t1[p] = fmaf(f4.x, w0, t1[p]);
            t1[p] = fmaf(f4.y, w1, t1[p]);
            t1[p] = fmaf(f4.z, w2, t1[p]);
            t1[p] = fmaf(f4.w, w3, t1[p]);
        }
    }

    // ---- layernorm (biased) + relu ------------------------------------
    float mean[8];
    {
        #pragma unroll
        for (int p = 0; p < 8; ++p) {
            float s = t1[p];
            for (int o = 32; o > 0; o >>= 1) s += __shfl_down(s, o, 64);
            if (lane == 0) red[wv_id][p] = s;
        }
        __syncthreads();
        #pragma unroll
        for (int p = 0; p < 8; ++p) mean[p] = (red[0][p] + red[1][p]) * (1.0f / 128.0f);
        __syncthreads();
        #pragma unroll
        for (int p = 0; p < 8; ++p) {
            float d = t1[p] - mean[p];
            float s = d * d;
            for (int o = 32; o > 0; o >>= 1) s += __shfl_down(s, o, 64);
            if (lane == 0) red[wv_id][p] = s;
        }
        __syncthreads();
    }
    #pragma unroll
    for (int p = 0; p < 8; ++p) {
        float var = (red[0][p] + red[1][p]) * (1.0f / 128.0f);
        float z = fmaxf((t1[p] - mean[p]) / sqrtf(var + 1e-5f), 0.0f);
        t1[p] = z;
    }
    __syncthreads();
    #pragma unroll
    for (int p = 0; p < 8; ++p) sh[p][j] = t1[p];
    __syncthreads();

    // ---- layer 3: t2 = z @ Wm2 + bm2 ----------------------------------
    float t2[8];
    #pragma unroll
    for (int p = 0; p < 8; ++p) t2[p] = bm2[j];
    for (int k = 0; k < 128; k += 4) {
        float w0 = Wm2[(k + 0) * 128 + j];
        float w1 = Wm2[(k + 1) * 128 + j];
        float w2 = Wm2[(k + 2) * 128 + j];
        float w3 = Wm2[(k + 3) * 128 + j];
        #pragma unroll
        for (int p = 0; p < 8; ++p) {
            const float4 f4 = *(const float4*)(&sh[p][k]);
            t2[p] = fmaf(f4.x, w0, t2[p]);
            t2[p] = fmaf(f4.y, w1, t2[p]);
            t2[p] = fmaf(f4.z, w2, t2[p]);
            t2[p] = fmaf(f4.w, w3, t2[p]);
        }
    }

    // ---- standardize (ddof=1) + nan_to_num ----------------------------
    float mu[8];
    {
        #pragma unroll
        for (int p = 0; p < 8; ++p) {
            float s = t2[p];
            for (int o = 32; o > 0; o >>= 1) s += __shfl_down(s, o, 64);
            if (lane == 0) red[wv_id][p] = s;
        }
        __syncthreads();
        #pragma unroll
        for (int p = 0; p < 8; ++p) mu[p] = (red[0][p] + red[1][p]) * (1.0f / 128.0f);
        __syncthreads();
        #pragma unroll
        for (int p = 0; p < 8; ++p) {
            float d = t2[p] - mu[p];
            float s = d * d;
            for (int o = 32; o > 0; o >>= 1) s += __shfl_down(s, o, 64);
            if (lane == 0) red[wv_id][p] = s;
        }
        __syncthreads();
    }
    #pragma unroll
    for (int p = 0; p < 8; ++p) {
        float sd = sqrtf((red[0][p] + red[1][p]) * (1.0f / 127.0f));
        float r = (t2[p] - mu[p]) / sd;
        if (!(fabsf(r) <= 3.402823466e38f)) {
            r = (r != r) ? 0.0f : ((r > 0.0f) ? 3.402823466e38f : -3.402823466e38f);
        }
        xout[(size_t)(row0 + p) * 128 + j] = r;
    }
}

// ---------------------------------------------------------------------------
// degree histogram over key = rel*N + src
// ---------------------------------------------------------------------------
__global__ void deg_kernel(const int* __restrict__ src, const int* __restrict__ rel,
                           int* __restrict__ deg_i)
{
    int e = blockIdx.x * 256 + threadIdx.x;
    if (e >= E_) return;
    atomicAdd(&deg_i[rel[e] * N_TOT + src[e]], 1);
}

__global__ void dinv_kernel(const int* __restrict__ deg_i, float* __restrict__ dinv)
{
    int i = blockIdx.x * 256 + threadIdx.x;
    if (i >= RN) return;
    int dg = deg_i[i];
    dinv[i] = (dg > 0) ? 1.0f / sqrtf((float)dg) : 0.0f;
}

// ---------------------------------------------------------------------------
// single-block exclusive scan of deg_i (RN elems) -> rp[RN+1]
// ---------------------------------------------------------------------------
__global__ __launch_bounds__(1024) void scan_kernel(const int* __restrict__ cnt,
                                                    int* __restrict__ rp)
{
    __shared__ int wsum[16];
    __shared__ int s_carry;
    const int t = threadIdx.x, lane = t & 63, w = t >> 6;
    if (t == 0) s_carry = 0;
    __syncthreads();
    const int CH = 8192;
    for (int base = 0; base < RN; base += CH) {
        int v[8]; int s = 0;
        const int i0 = base + t * 8;
        #pragma unroll
        for (int i = 0; i < 8; ++i) { int ii = i0 + i; v[i] = (ii < RN) ? cnt[ii] : 0; s += v[i]; }
        int sc = s;
        #pragma unroll
        for (int o = 1; o < 64; o <<= 1) { int tmp = __shfl_up(sc, o, 64); if (lane >= o) sc += tmp; }
        if (lane == 63) wsum[w] = sc;
        __syncthreads();
        int woff = 0;
        for (int i = 0; i < w; ++i) woff += wsum[i];
        int run = s_carry + woff + (sc - s);
        #pragma unroll
        for (int i = 0; i < 8; ++i) { int ii = i0 + i; if (ii < RN) rp[ii] = run; run += v[i]; }
        int chunk_total = woff + sc;   // valid for t==1023
        __syncthreads();
        if (t == 1023) s_carry += chunk_total;
        __syncthreads();
    }
    if (threadIdx.x == 0) rp[RN] = s_carry;
}

// ---------------------------------------------------------------------------
// counting-sort scatter into CSR keyed by rel*N+src
// ---------------------------------------------------------------------------
__global__ void scatter_kernel(const int* __restrict__ src, const int* __restrict__ dst,
                               const int* __restrict__ rel, const int* __restrict__ rp,
                               int* __restrict__ fill, const int* __restrict__ deg_i,
                               const float* __restrict__ dinv,
                               int* __restrict__ csr_dst, float* __restrict__ csr_w,
                               float* __restrict__ csr_edinv)
{
    int e = blockIdx.x * 256 + threadIdx.x;
    if (e >= E_) return;
    int s = src[e], r = rel[e], d = dst[e];
    int key = r * N_TOT + s;
    int pos = rp[key] + atomicAdd(&fill[key], 1);
    csr_dst[pos] = d;
    csr_w[pos] = 1.0f / (float)deg_i[key];
    csr_edinv[pos] = dinv[key] * dinv[r * N_TOT + d];
}

// ---------------------------------------------------------------------------
// tv: per-wave node loop; per-lane partial accumulators for node/edge terms
// ---------------------------------------------------------------------------
__global__ __launch_bounds__(256) void tv_kernel(
    const float* __restrict__ x, const int* __restrict__ rp,
    const int* __restrict__ csr_dst, const float* __restrict__ csr_edinv,
    const int* __restrict__ act, int k, float* __restrict__ accbuf)
{
    if (act[k] == 0) return;
    const int lane = threadIdx.x & 63;
    const int wv = threadIdx.x >> 6;
    const int wid = blockIdx.x * 4 + wv;
    const int nw = gridDim.x * 4;
    float na[5] = {0, 0, 0, 0, 0};
    float ea[5] = {0, 0, 0, 0, 0};
    for (int n = wid; n < N_TOT; n += nw) {
        const float2 xs = ((const float2*)(x + (size_t)n * 128))[lane];
        const float p = fmaf(xs.x, xs.x, xs.y * xs.y);
        #pragma unroll
        for (int r = 0; r < 5; ++r) {
            const int e0 = rp[r * N_TOT + n];
            const int e1 = rp[r * N_TOT + n + 1];
            if (e1 > e0) na[r] += p;
            float acc = 0.0f;
            for (int e = e0; e < e1; ++e) {
                const int dn = csr_dst[e];
                const float2 xd = ((const float2*)(x + (size_t)dn * 128))[lane];
                const float pe = fmaf(xs.x, xd.x, xs.y * xd.y);
                acc = fmaf(csr_edinv[e], pe, acc);
            }
            ea[r] += acc;
        }
    }
    __shared__ float sacc[4][10];
    #pragma unroll
    for (int r = 0; r < 5; ++r) {
        float a = na[r], b = ea[r];
        for (int o = 32; o > 0; o >>= 1) {
            a += __shfl_down(a, o, 64);
            b += __shfl_down(b, o, 64);
        }
        if (lane == 0) { sacc[wv][r] = a; sacc[wv][5 + r] = b; }
    }
    __syncthreads();
    if (threadIdx.x < 10) {
        float t = sacc[0][threadIdx.x] + sacc[1][threadIdx.x] +
                  sacc[2][threadIdx.x] + sacc[3][threadIdx.x];
        atomicAdd(&accbuf[threadIdx.x], t);
    }
}

// ---------------------------------------------------------------------------
// scalar: w from accumulators, mirror descent on u, still flag
// ---------------------------------------------------------------------------
__global__ void scalar_kernel(const float* __restrict__ accbuf, float* __restrict__ u,
                              float* __restrict__ c_l1, int* __restrict__ act, int k)
{
    if (threadIdx.x != 0 || blockIdx.x != 0) return;
    int a = act[k];
    double w[5]; double l1 = 0.0;
    for (int r = 0; r < 5; ++r) {
        w[r] = ((double)accbuf[r] - (double)accbuf[5 + r]) / 30000.0;
        l1 += fabs(w[r]);
    }
    if (k == 0) c_l1[0] = (float)l1;
    if (!a) { act[k + 1] = 0; return; }
    double fi = l1 + 3.0;                       // ratio = 2*L2/L1 = 3
    double uu[5];
    for (int r = 0; r < 5; ++r) uu[r] = (double)u[r];
    bool mact = true;
    const double twolog5 = 3.2188758248682006;  // 2*ln(5)
    for (int t = 1; t <= 20; ++t) {
        double T = sqrt(twolog5 / ((double)t * fi * fi));
        double ta[5], sum = 0.0;
        for (int r = 0; r < 5; ++r) { ta[r] = uu[r] * exp(-T * (3.0 * uu[r] + w[r])); sum += ta[r]; }
        double diff = 0.0;
        for (int r = 0; r < 5; ++r) { double un = ta[r] / sum; double d0 = uu[r] - un; diff += d0 * d0; ta[r] = un; }
        diff = sqrt(diff);
        if (mact) { for (int r = 0; r < 5; ++r) uu[r] = ta[r]; }
        mact = mact && (diff >= 1e-3);
    }
    for (int r = 0; r < 5; ++r) u[r] = (float)uu[r];
    int still = (l1 / (double)c_l1[0] >= 0.3) ? 1 : 0;
    act[k + 1] = still;
}

// ---------------------------------------------------------------------------
// fused msg + update, ping-pong: xout = xin/21 + (20/21)*msg  (or copy when
// inactive). Always writes xout so the final buffer is statically known.
// ---------------------------------------------------------------------------
__global__ __launch_bounds__(256) void msg_upd_kernel(
    const float* __restrict__ xin, float* __restrict__ xout,
    const int* __restrict__ rp, const int* __restrict__ csr_dst,
    const float* __restrict__ csr_w, const float* __restrict__ ug,
    const int* __restrict__ act, int k)
{
    const int a = act[k + 1];
    const int lane = threadIdx.x & 63;
    const int wid = blockIdx.x * 4 + (threadIdx.x >> 6);
    const int nw = gridDim.x * 4;
    if (a) {
        const float u0 = ug[0], u1 = ug[1], u2 = ug[2], u3 = ug[3], u4 = ug[4];
        for (int n = wid; n < N_TOT; n += nw) {
            const float2 xs = ((const float2*)(xin + (size_t)n * 128))[lane];
            float ax = 0.0f, ay = 0.0f;
            #pragma unroll
            for (int r = 0; r < 5; ++r) {
                const float ur = (r == 0) ? u0 : (r == 1) ? u1 : (r == 2) ? u2 : (r == 3) ? u3 : u4;
                const int e0 = rp[r * N_TOT + n];
                const int e1 = rp[r * N_TOT + n + 1];
                for (int e = e0; e < e1; ++e) {
                    const float wgt = ur * csr_w[e];
                    const int dn = csr_dst[e];
                    const float2 xd = ((const float2*)(xin + (size_t)dn * 128))[lane];
                    ax = fmaf(wgt, xd.x, ax);
                    ay = fmaf(wgt, xd.y, ay);
                }
            }
            const float ci = 1.0f / 21.0f, cb = (float)(20.0 / 21.0);
            ((float2*)(xout + (size_t)n * 128))[lane] =
                make_float2(fmaf(cb, ax, xs.x * ci), fmaf(cb, ay, xs.y * ci));
        }
    } else {
        for (int n = wid; n < N_TOT; n += nw) {
            const float2 xs = ((const float2*)(xin + (size_t)n * 128))[lane];
            ((float2*)(xout + (size_t)n * 128))[lane] = xs;
        }
    }
}

// ---------------------------------------------------------------------------
// epilogue: logits = x@Wout + bout ; write logits, x, u
// ---------------------------------------------------------------------------
__global__ __launch_bounds__(256) void final_kernel(const float* __restrict__ x,
                                                    const float* __restrict__ Wout,
                                                    const float* __restrict__ bout,
                                                    const float* __restrict__ ug,
                                                    float* __restrict__ out)
{
    const int nl = threadIdx.x >> 7;              // node-local 0/1
    const int n = blockIdx.x * 2 + nl;
    const int j = threadIdx.x & 127;
    const int lane = threadIdx.x & 63;
    const int wv = threadIdx.x >> 6;              // 0..3
    float xv = x[(size_t)n * 128 + j];
    out[(size_t)NC_ + (size_t)n * 128 + j] = xv;  // x output
    float p[8];
    #pragma unroll
    for (int c = 0; c < 8; ++c) p[c] = xv * Wout[j * 8 + c];
    #pragma unroll
    for (int c = 0; c < 8; ++c)
        for (int o = 32; o > 0; o >>= 1) p[c] += __shfl_down(p[c], o, 64);
    __shared__ float sp[4][8];
    if (lane == 0) {
        #pragma unroll
        for (int c = 0; c < 8; ++c) sp[wv][c] = p[c];
    }
    __syncthreads();
    if (j < 8) {
        int c = j;
        out[(size_t)n * 8 + c] = bout[c] + sp[2 * nl][c] + sp[2 * nl + 1][c];
    }
    if (blockIdx.x == 0 && threadIdx.x < 5)
        out[(size_t)NC_ + (size_t)NX_ + threadIdx.x] = ug[threadIdx.x];
}

// ---------------------------------------------------------------------------
extern "C" void kernel_launch(void* const* d_in, const int* in_sizes, int n_in,
                              void* d_out, int out_size, void* d_ws, size_t ws_size,
                              hipStream_t stream)
{
    const float* feat0 = (const float*)d_in[0];
    const float* feat1 = (const float*)d_in[1];
    const float* W0   = (const float*)d_in[2];
    const float* b0   = (const float*)d_in[3];
    const float* W1   = (const float*)d_in[4];
    const float* b1   = (const float*)d_in[5];
    const float* Wm1  = (const float*)d_in[6];
    const float* bm1  = (const float*)d_in[7];
    const float* Wm2  = (const float*)d_in[8];
    const float* bm2  = (const float*)d_in[9];
    const float* Wout = (const float*)d_in[10];
    const float* bout = (const float*)d_in[11];
    const int* src = (const int*)d_in[12];
    const int* dst = (const int*)d_in[13];
    const int* rel = (const int*)d_in[14];
    float* out = (float*)d_out;

    // workspace layout (~39 MiB total)
    char* p = (char*)d_ws;
    auto alloc = [&](size_t bytes) { char* q = p; p += (bytes + 255) & ~(size_t)255; return q; };
    float* xbuf      = (float*)alloc((size_t)NX_ * 4);
    float* xalt      = (float*)alloc((size_t)NX_ * 4);
    int*   deg_i     = (int*)  alloc((size_t)RN * 4);
    float* dinv      = (float*)alloc((size_t)RN * 4);
    int*   rp        = (int*)  alloc(((size_t)RN + 1) * 4);
    int*   fill      = (int*)  alloc((size_t)RN * 4);
    int*   csr_dst   = (int*)  alloc((size_t)E_ * 4);
    float* csr_w     = (float*)alloc((size_t)E_ * 4);
    float* csr_edinv = (float*)alloc((size_t)E_ * 4);
    float* accbuf    = (float*)alloc(64);
    float* ug        = (float*)alloc(64);
    float* c_l1      = (float*)alloc(64);
    int*   act       = (int*)  alloc(64);

    hipMemsetAsync(deg_i, 0, (size_t)RN * 4, stream);
    hipMemsetAsync(fill, 0, (size_t)RN * 4, stream);
    init_kernel<<<1, 64, 0, stream>>>(ug, act);

    mlp_kernel<<<N_TOT / 8, 128, 0, stream>>>(feat0, feat1, W0, b0, W1, b1,
                                              Wm1, bm1, Wm2, bm2, xbuf);

    deg_kernel<<<(E_ + 255) / 256, 256, 0, stream>>>(src, rel, deg_i);
    dinv_kernel<<<(RN + 255) / 256, 256, 0, stream>>>(deg_i, dinv);
    scan_kernel<<<1, 1024, 0, stream>>>(deg_i, rp);
    scatter_kernel<<<(E_ + 255) / 256, 256, 0, stream>>>(src, dst, rel, rp, fill,
                                                         deg_i, dinv,
                                                         csr_dst, csr_w, csr_edinv);

    float* xa = xbuf;
    float* xb = xalt;
    for (int k = 0; k < 8; ++k) {
        hipMemsetAsync(accbuf, 0, 64, stream);
        tv_kernel<<<2048, 256, 0, stream>>>(xa, rp, csr_dst, csr_edinv, act, k, accbuf);
        scalar_kernel<<<1, 64, 0, stream>>>(accbuf, ug, c_l1, act, k);
        msg_upd_kernel<<<2048, 256, 0, stream>>>(xa, xb, rp, csr_dst, csr_w, ug, act, k);
        float* t = xa; xa = xb; xb = t;
    }
    // after 8 swaps, xa == xbuf

    final_kernel<<<N_TOT / 2, 256, 0, stream>>>(xa, Wout, bout, ug, out);
}